// Round 7
// baseline (590.912 us; speedup 1.0000x reference)
//
#include <hip/hip_runtime.h>
#include <math.h>

#define N_NODES 50000
#define N_EDGES 400000
#define F_DIM   128
#define N_RBF   20
#define WPAD    21          // padded weights-per-f (odd -> bank-conflict-free, proven R6)
#define NPB     4           // nodes per block (512 threads)
#define SCAN_B  256
#define N_CHUNK ((N_NODES + SCAN_B - 1) / SCAN_B)   // 196

// ---------------------------------------------------------------------------
// phi_table[t] = silu(emb_table[t] @ w_phi1 + b_phi1) @ w_phi2 + b_phi2
// ---------------------------------------------------------------------------
__global__ void phi_table_kernel(const float* __restrict__ emb_table,
                                 const float* __restrict__ w_phi1,
                                 const float* __restrict__ b_phi1,
                                 const float* __restrict__ w_phi2,
                                 const float* __restrict__ b_phi2,
                                 float* __restrict__ phi_table) {
    __shared__ float emb_s[F_DIM];
    __shared__ float h_s[F_DIM];
    const int t = blockIdx.x;
    const int o = threadIdx.x;
    if (o < F_DIM) emb_s[o] = emb_table[t * F_DIM + o];
    __syncthreads();
    if (o < F_DIM) {
        float acc = b_phi1[o];
#pragma unroll 8
        for (int k = 0; k < F_DIM; ++k)
            acc = fmaf(emb_s[k], w_phi1[k * F_DIM + o], acc);
        h_s[o] = acc / (1.0f + expf(-acc));   // silu
    }
    __syncthreads();
    float a2 = b_phi2[o];
#pragma unroll 8
    for (int k = 0; k < F_DIM; ++k)
        a2 = fmaf(h_s[k], w_phi2[k * (3 * F_DIM) + o], a2);
    phi_table[t * (3 * F_DIM) + o] = a2;
}

__global__ void count_kernel(const int* __restrict__ edst, int* __restrict__ counts) {
    const int e = blockIdx.x * blockDim.x + threadIdx.x;
    if (e < N_EDGES) atomicAdd(&counts[edst[e]], 1);
}

__global__ void scan_partial_kernel(const int* __restrict__ counts,
                                    int* __restrict__ partial,
                                    int* __restrict__ chunk_sums) {
    __shared__ int s[SCAN_B];
    const int tid = threadIdx.x;
    const int gid = blockIdx.x * SCAN_B + tid;
    const int v = (gid < N_NODES) ? counts[gid] : 0;
    s[tid] = v;
    __syncthreads();
    for (int d = 1; d < SCAN_B; d <<= 1) {
        const int t = (tid >= d) ? s[tid - d] : 0;
        __syncthreads();
        s[tid] += t;
        __syncthreads();
    }
    if (gid < N_NODES) partial[gid] = s[tid] - v;
    if (tid == SCAN_B - 1) chunk_sums[blockIdx.x] = s[tid];
}

__global__ void scan_sums_kernel(int* __restrict__ chunk_sums,
                                 int* __restrict__ chunk_pref) {
    __shared__ int s[SCAN_B];
    const int tid = threadIdx.x;
    const int v = (tid < N_CHUNK) ? chunk_sums[tid] : 0;
    s[tid] = v;
    __syncthreads();
    for (int d = 1; d < SCAN_B; d <<= 1) {
        const int t = (tid >= d) ? s[tid - d] : 0;
        __syncthreads();
        s[tid] += t;
        __syncthreads();
    }
    if (tid < N_CHUNK) chunk_pref[tid] = s[tid] - v;
}

__global__ void finalize_offsets_kernel(const int* __restrict__ partial,
                                        const int* __restrict__ chunk_pref,
                                        int* __restrict__ offsets,
                                        int* __restrict__ cursor) {
    const int i = blockIdx.x * blockDim.x + threadIdx.x;
    if (i >= N_NODES) return;
    const int o = partial[i] + chunk_pref[i >> 8];
    offsets[i] = o;
    cursor[i]  = o;
}

// ---------------------------------------------------------------------------
// Edge-parallel precompute + CSR fill. Per edge, one 32B record at slot p:
//   rec[2p]   = (px, py, pz, d)
//   rec[2p+1] = (j, t, sin(a)/d, 2*cos(a))   [a = pi*d/5]
// ---------------------------------------------------------------------------
__global__ void edge_pre_kernel(const float* __restrict__ pos,
                                const int* __restrict__ z,
                                const int* __restrict__ esrc,
                                const int* __restrict__ edst,
                                int* __restrict__ cursor,
                                float4* __restrict__ rec) {
    const int e = blockIdx.x * blockDim.x + threadIdx.x;
    if (e >= N_EDGES) return;
    const int j = esrc[e];
    const int i = edst[e];
    const int p = atomicAdd(&cursor[i], 1);

    const float px = pos[3 * i + 0] - pos[3 * j + 0];
    const float py = pos[3 * i + 1] - pos[3 * j + 1];
    const float pz = pos[3 * i + 2] - pos[3 * j + 2];
    const float d = sqrtf(px * px + py * py + pz * pz);
    const float inv_d = 1.0f / d;

    float sa, ca;
    sincosf(0.6283185307179586f * d, &sa, &ca);   // pi*d/5

    rec[2 * p] = make_float4(px, py, pz, d);
    float4 b;
    b.x = __int_as_float(j);
    b.y = __int_as_float(z[j]);
    b.z = sa * inv_d;
    b.w = 2.0f * ca;
    rec[2 * p + 1] = b;
}

// ---------------------------------------------------------------------------
// Gather: 128-thread group per node, NPB=4 nodes per 512-thread block.
// Thread f owns outputs f, 128+f, 256+f.
//
// R6 post-mortem: conflict fix landed (1.8e7 -> 0) with zero time delta ->
// conflicts were latency-hidden; the real regression R4-R6 was occupancy
// (VGPR 88-96 -> 19-21% vs R1's 52 -> 39%). R7 = R1's measured-best scalar
// structure VERBATIM (distance-1 rec/eq/phi pipeline, lean live state),
// with exactly one substitution: weights come from LDS (WPAD=21 layout,
// 0-conflict) via immediate-offset ds_read instead of 60 global loads +
// ~40 addr-VALU per edge. Plus 4 nodes/block to halve dispatch count and
// amortize the LDS stage.
// ---------------------------------------------------------------------------
__global__ void __launch_bounds__(512, 2)
gather_kernel(const float* __restrict__ eq,
              const float* __restrict__ emb_table,
              const float* __restrict__ phi_table,
              const float* __restrict__ w_rbf,
              const float* __restrict__ b_rbf,
              const int* __restrict__ z,
              const float4* __restrict__ rec,
              const int* __restrict__ offsets,
              const int* __restrict__ counts,
              float* __restrict__ out_emb,
              float* __restrict__ out_eq) {
    __shared__ float wlds[3 * F_DIM * WPAD];   // wT[c][f*21+n], 32256 B
    const int tid = threadIdx.x;

    // one-time stage: coalesced global read, stride-21 LDS write (2-way, free)
    for (int idx = tid; idx < 3 * F_DIM * N_RBF; idx += 512) {
        const int n = idx / (3 * F_DIM);
        const int m = idx - n * (3 * F_DIM);        // 0..383
        const int c = m >> 7;                        // channel
        const int ff = m & 127;
        wlds[c * (F_DIM * WPAD) + ff * WPAD + n] = w_rbf[idx];
    }
    __syncthreads();

    const int grp = tid >> 7;          // 0..3
    const int f   = tid & 127;
    const int i   = blockIdx.x * NPB + grp;
    if (i >= N_NODES) return;

    const int start = offsets[i];
    const int cnt   = counts[i];

    const float br1 = b_rbf[f];
    const float br2 = b_rbf[F_DIM + f];
    const float br3 = b_rbf[2 * F_DIM + f];
    // one base, all channel/n offsets are compile-time immediates
    const float* wl1 = &wlds[f * WPAD];
    const float* wl2 = wl1 + F_DIM * WPAD;
    const float* wl3 = wl1 + 2 * F_DIM * WPAD;

    float accE = 0.f, ax = 0.f, ay = 0.f, az = 0.f;

    float4 A0, B0;
    float eq0, eq1, eq2, ph0, ph1, ph2;
    if (cnt > 0) {
        A0 = rec[2 * start];
        B0 = rec[2 * start + 1];
        const int j0 = __float_as_int(B0.x);
        const int t0 = __float_as_int(B0.y);
        const float* ej = eq + ((size_t)j0 * F_DIM + f) * 3;
        eq0 = ej[0]; eq1 = ej[1]; eq2 = ej[2];
        const float* pt = phi_table + t0 * (3 * F_DIM);
        ph0 = pt[f]; ph1 = pt[F_DIM + f]; ph2 = pt[2 * F_DIM + f];
    }

    for (int k = 0; k < cnt; ++k) {
        // prefetch next edge's record + gathers (overlaps the FMA block)
        float4 A1, B1;
        float neq0, neq1, neq2, nph0, nph1, nph2;
        if (k + 1 < cnt) {
            const int p1 = start + k + 1;
            A1 = rec[2 * p1];
            B1 = rec[2 * p1 + 1];
            const int j1 = __float_as_int(B1.x);
            const int t1 = __float_as_int(B1.y);
            const float* ej = eq + ((size_t)j1 * F_DIM + f) * 3;
            neq0 = ej[0]; neq1 = ej[1]; neq2 = ej[2];
            const float* pt = phi_table + t1 * (3 * F_DIM);
            nph0 = pt[f]; nph1 = pt[F_DIM + f]; nph2 = pt[2 * F_DIM + f];
        }

        // inner block: 60 imm-offset ds_read (fusable to ds_read2_b32)
        // + 80 FMA, zero VMEM, zero addr VALU
        float W1 = br1, W2 = br2, W3 = br3;
        float tm1 = 0.0f, tc = B0.z;
        const float twoc = B0.w;
#pragma unroll
        for (int n = 0; n < N_RBF; ++n) {
            W1 = fmaf(tc, wl1[n], W1);
            W2 = fmaf(tc, wl2[n], W2);
            W3 = fmaf(tc, wl3[n], W3);
            const float tn = fmaf(twoc, tc, -tm1);
            tm1 = tc; tc = tn;
        }

        accE += ph0 * W1;
        const float s2 = ph1 * W2;
        const float s3 = ph2 * W3 * A0.w;
        ax = fmaf(eq0, s2, fmaf(s3, A0.x, ax));
        ay = fmaf(eq1, s2, fmaf(s3, A0.y, ay));
        az = fmaf(eq2, s2, fmaf(s3, A0.z, az));

        if (k + 1 < cnt) {
            A0 = A1; B0 = B1;
            eq0 = neq0; eq1 = neq1; eq2 = neq2;
            ph0 = nph0; ph1 = nph1; ph2 = nph2;
        }
    }

    out_emb[(size_t)i * F_DIM + f] = emb_table[z[i] * F_DIM + f] + accE;

    const float* ei = eq     + ((size_t)i * F_DIM + f) * 3;
    float*       od = out_eq + ((size_t)i * F_DIM + f) * 3;
    od[0] = ei[0] + ax;
    od[1] = ei[1] + ay;
    od[2] = ei[2] + az;
}

// ---------------------------------------------------------------------------
extern "C" void kernel_launch(void* const* d_in, const int* in_sizes, int n_in,
                              void* d_out, int out_size, void* d_ws, size_t ws_size,
                              hipStream_t stream) {
    const float* pos       = (const float*)d_in[0];
    const float* eq        = (const float*)d_in[1];
    const float* emb_table = (const float*)d_in[2];
    const float* w_phi1    = (const float*)d_in[3];
    const float* b_phi1    = (const float*)d_in[4];
    const float* w_phi2    = (const float*)d_in[5];
    const float* b_phi2    = (const float*)d_in[6];
    const float* w_rbf     = (const float*)d_in[7];
    const float* b_rbf     = (const float*)d_in[8];
    const int*   z         = (const int*)d_in[9];
    const int*   esrc      = (const int*)d_in[10];
    const int*   edst      = (const int*)d_in[11];

    float* out_emb = (float*)d_out;                               // [N, F]
    float* out_eq  = (float*)d_out + (size_t)N_NODES * F_DIM;     // [N, F, 3]

    // workspace layout (16B-aligned chunks)
    char* ws = (char*)d_ws;
    float4* rec        = (float4*)ws;  ws += (size_t)N_EDGES * 32;
    float*  phi_table  = (float*)ws;   ws += 100 * 3 * F_DIM * 4;
    int*    counts     = (int*)ws;     ws += N_NODES * 4;
    int*    partial    = (int*)ws;     ws += N_NODES * 4;
    int*    offsets    = (int*)ws;     ws += N_NODES * 4;
    int*    cursor     = (int*)ws;     ws += N_NODES * 4;
    int*    chunk_sums = (int*)ws;     ws += SCAN_B * 4;
    int*    chunk_pref = (int*)ws;     ws += SCAN_B * 4;

    hipMemsetAsync(counts, 0, N_NODES * sizeof(int), stream);
    phi_table_kernel<<<100, 3 * F_DIM, 0, stream>>>(emb_table, w_phi1, b_phi1,
                                                    w_phi2, b_phi2, phi_table);
    count_kernel<<<(N_EDGES + 255) / 256, 256, 0, stream>>>(edst, counts);
    scan_partial_kernel<<<N_CHUNK, SCAN_B, 0, stream>>>(counts, partial, chunk_sums);
    scan_sums_kernel<<<1, SCAN_B, 0, stream>>>(chunk_sums, chunk_pref);
    finalize_offsets_kernel<<<(N_NODES + 255) / 256, 256, 0, stream>>>(
        partial, chunk_pref, offsets, cursor);
    edge_pre_kernel<<<(N_EDGES + 255) / 256, 256, 0, stream>>>(
        pos, z, esrc, edst, cursor, rec);
    gather_kernel<<<(N_NODES + NPB - 1) / NPB, NPB * 128, 0, stream>>>(
        eq, emb_table, phi_table, w_rbf, b_rbf, z, rec,
        offsets, counts, out_emb, out_eq);
}

// Round 8
// 505.778 us; speedup vs baseline: 1.1683x; 1.1683x over previous
//
#include <hip/hip_runtime.h>
#include <math.h>

#define N_NODES 50000
#define N_EDGES 400000
#define F_DIM   128
#define N_RBF   20
#define SCAN_B  256
#define N_CHUNK ((N_NODES + SCAN_B - 1) / SCAN_B)   // 196

// ---------------------------------------------------------------------------
// phi_table[t] = silu(emb_table[t] @ w_phi1 + b_phi1) @ w_phi2 + b_phi2
// ---------------------------------------------------------------------------
__global__ void phi_table_kernel(const float* __restrict__ emb_table,
                                 const float* __restrict__ w_phi1,
                                 const float* __restrict__ b_phi1,
                                 const float* __restrict__ w_phi2,
                                 const float* __restrict__ b_phi2,
                                 float* __restrict__ phi_table) {
    __shared__ float emb_s[F_DIM];
    __shared__ float h_s[F_DIM];
    const int t = blockIdx.x;
    const int o = threadIdx.x;
    if (o < F_DIM) emb_s[o] = emb_table[t * F_DIM + o];
    __syncthreads();
    if (o < F_DIM) {
        float acc = b_phi1[o];
#pragma unroll 8
        for (int k = 0; k < F_DIM; ++k)
            acc = fmaf(emb_s[k], w_phi1[k * F_DIM + o], acc);
        h_s[o] = acc / (1.0f + expf(-acc));   // silu
    }
    __syncthreads();
    float a2 = b_phi2[o];
#pragma unroll 8
    for (int k = 0; k < F_DIM; ++k)
        a2 = fmaf(h_s[k], w_phi2[k * (3 * F_DIM) + o], a2);
    phi_table[t * (3 * F_DIM) + o] = a2;
}

// ---------------------------------------------------------------------------
// Transpose w_rbf[20][3][128] -> wT[20][128][3] so the 3 channel weights for
// a fixed (n, f) are ADJACENT: one global_load_dwordx3 per n in the gather
// inner loop instead of 3 scattered dwords. 30 KB, stays L1-resident.
// ---------------------------------------------------------------------------
__global__ void transpose_w_kernel(const float* __restrict__ w_rbf,
                                   float* __restrict__ wT) {
    const int n = blockIdx.x;          // 0..19
    const int m = threadIdx.x;         // 0..383
    const int c = m >> 7;              // channel 0..2
    const int f = m & 127;
    wT[((size_t)n * F_DIM + f) * 3 + c] = w_rbf[n * (3 * F_DIM) + m];
}

__global__ void count_kernel(const int* __restrict__ edst, int* __restrict__ counts) {
    const int e = blockIdx.x * blockDim.x + threadIdx.x;
    if (e < N_EDGES) atomicAdd(&counts[edst[e]], 1);
}

__global__ void scan_partial_kernel(const int* __restrict__ counts,
                                    int* __restrict__ partial,
                                    int* __restrict__ chunk_sums) {
    __shared__ int s[SCAN_B];
    const int tid = threadIdx.x;
    const int gid = blockIdx.x * SCAN_B + tid;
    const int v = (gid < N_NODES) ? counts[gid] : 0;
    s[tid] = v;
    __syncthreads();
    for (int d = 1; d < SCAN_B; d <<= 1) {
        const int t = (tid >= d) ? s[tid - d] : 0;
        __syncthreads();
        s[tid] += t;
        __syncthreads();
    }
    if (gid < N_NODES) partial[gid] = s[tid] - v;
    if (tid == SCAN_B - 1) chunk_sums[blockIdx.x] = s[tid];
}

__global__ void scan_sums_kernel(int* __restrict__ chunk_sums,
                                 int* __restrict__ chunk_pref) {
    __shared__ int s[SCAN_B];
    const int tid = threadIdx.x;
    const int v = (tid < N_CHUNK) ? chunk_sums[tid] : 0;
    s[tid] = v;
    __syncthreads();
    for (int d = 1; d < SCAN_B; d <<= 1) {
        const int t = (tid >= d) ? s[tid - d] : 0;
        __syncthreads();
        s[tid] += t;
        __syncthreads();
    }
    if (tid < N_CHUNK) chunk_pref[tid] = s[tid] - v;
}

__global__ void finalize_offsets_kernel(const int* __restrict__ partial,
                                        const int* __restrict__ chunk_pref,
                                        int* __restrict__ offsets,
                                        int* __restrict__ cursor) {
    const int i = blockIdx.x * blockDim.x + threadIdx.x;
    if (i >= N_NODES) return;
    const int o = partial[i] + chunk_pref[i >> 8];
    offsets[i] = o;
    cursor[i]  = o;
}

// ---------------------------------------------------------------------------
// Edge-parallel precompute + CSR fill. Per edge, one 32B record at slot p:
//   rec[2p]   = (px, py, pz, d)
//   rec[2p+1] = (j, t, sin(a)/d, 2*cos(a))   [a = pi*d/5]
// ---------------------------------------------------------------------------
__global__ void edge_pre_kernel(const float* __restrict__ pos,
                                const int* __restrict__ z,
                                const int* __restrict__ esrc,
                                const int* __restrict__ edst,
                                int* __restrict__ cursor,
                                float4* __restrict__ rec) {
    const int e = blockIdx.x * blockDim.x + threadIdx.x;
    if (e >= N_EDGES) return;
    const int j = esrc[e];
    const int i = edst[e];
    const int p = atomicAdd(&cursor[i], 1);

    const float px = pos[3 * i + 0] - pos[3 * j + 0];
    const float py = pos[3 * i + 1] - pos[3 * j + 1];
    const float pz = pos[3 * i + 2] - pos[3 * j + 2];
    const float d = sqrtf(px * px + py * py + pz * pz);
    const float inv_d = 1.0f / d;

    float sa, ca;
    sincosf(0.6283185307179586f * d, &sa, &ca);   // pi*d/5

    rec[2 * p] = make_float4(px, py, pz, d);
    float4 b;
    b.x = __int_as_float(j);
    b.y = __int_as_float(z[j]);
    b.z = sa * inv_d;
    b.w = 2.0f * ca;
    rec[2 * p + 1] = b;
}

// ---------------------------------------------------------------------------
// Gather: 128-thread group per node (2/block). Thread f owns outputs
// f, 128+f, 256+f.
//
// R7 post-mortem: relocating the 60 weight accesses (regs/LDS) never wins —
// the issue count is what costs (~240 of R1's ~464 cyc/edge at ~4cyc/VMEM).
// R8 = R1's measured-best structure VERBATIM, with the access COUNT cut 3x:
// wT[n][f][3] puts the 3 channel weights adjacent -> one dwordx3 per n
// (20 loads/edge instead of 60), same 4-line/load coalescing, zero addr
// VALU (7 hoisted SGPR bases + immediate offsets). eq reads and out_eq
// accesses also go float3 (1 dwordx3 instead of 3 dwords).
// ---------------------------------------------------------------------------
__global__ void __launch_bounds__(256, 2)
gather_kernel(const float* __restrict__ eq,
              const float* __restrict__ emb_table,
              const float* __restrict__ phi_table,
              const float* __restrict__ wT,
              const float* __restrict__ b_rbf,
              const int* __restrict__ z,
              const float4* __restrict__ rec,
              const int* __restrict__ offsets,
              const int* __restrict__ counts,
              float* __restrict__ out_emb,
              float* __restrict__ out_eq) {
    const int tid = threadIdx.x;
    const int grp = tid >> 7;
    const int f   = tid & 127;
    const int i   = blockIdx.x * 2 + grp;
    if (i >= N_NODES) return;

    const int start = offsets[i];
    const int cnt   = counts[i];

    const float br1 = b_rbf[f];
    const float br2 = b_rbf[F_DIM + f];
    const float br3 = b_rbf[2 * F_DIM + f];
    const float3* wtf = (const float3*)wT + f;   // + n*F_DIM per step

    float accE = 0.f, ax = 0.f, ay = 0.f, az = 0.f;

    float4 A0, B0;
    float3 eqv;
    float ph0, ph1, ph2;
    if (cnt > 0) {
        A0 = rec[2 * start];
        B0 = rec[2 * start + 1];
        const int j0 = __float_as_int(B0.x);
        const int t0 = __float_as_int(B0.y);
        eqv = *(const float3*)(eq + ((size_t)j0 * F_DIM + f) * 3);
        const float* pt = phi_table + t0 * (3 * F_DIM);
        ph0 = pt[f]; ph1 = pt[F_DIM + f]; ph2 = pt[2 * F_DIM + f];
    }

    for (int k = 0; k < cnt; ++k) {
        // prefetch next edge's record + gathers (overlaps the FMA block)
        float4 A1, B1;
        float3 neqv;
        float nph0, nph1, nph2;
        if (k + 1 < cnt) {
            const int p1 = start + k + 1;
            A1 = rec[2 * p1];
            B1 = rec[2 * p1 + 1];
            const int j1 = __float_as_int(B1.x);
            const int t1 = __float_as_int(B1.y);
            neqv = *(const float3*)(eq + ((size_t)j1 * F_DIM + f) * 3);
            const float* pt = phi_table + t1 * (3 * F_DIM);
            nph0 = pt[f]; nph1 = pt[F_DIM + f]; nph2 = pt[2 * F_DIM + f];
        }

        // inner block: 20 dwordx3 weight loads (imm offsets) + 80 FMA
        float W1 = br1, W2 = br2, W3 = br3;
        float tm1 = 0.0f, tc = B0.z;
        const float twoc = B0.w;
#pragma unroll
        for (int n = 0; n < N_RBF; ++n) {
            const float3 w = wtf[n * F_DIM];
            W1 = fmaf(tc, w.x, W1);
            W2 = fmaf(tc, w.y, W2);
            W3 = fmaf(tc, w.z, W3);
            const float tn = fmaf(twoc, tc, -tm1);
            tm1 = tc; tc = tn;
        }

        accE += ph0 * W1;
        const float s2 = ph1 * W2;
        const float s3 = ph2 * W3 * A0.w;
        ax = fmaf(eqv.x, s2, fmaf(s3, A0.x, ax));
        ay = fmaf(eqv.y, s2, fmaf(s3, A0.y, ay));
        az = fmaf(eqv.z, s2, fmaf(s3, A0.z, az));

        if (k + 1 < cnt) {
            A0 = A1; B0 = B1;
            eqv = neqv;
            ph0 = nph0; ph1 = nph1; ph2 = nph2;
        }
    }

    out_emb[(size_t)i * F_DIM + f] = emb_table[z[i] * F_DIM + f] + accE;

    const float3 ei = *(const float3*)(eq + ((size_t)i * F_DIM + f) * 3);
    float3 o3;
    o3.x = ei.x + ax;
    o3.y = ei.y + ay;
    o3.z = ei.z + az;
    *(float3*)(out_eq + ((size_t)i * F_DIM + f) * 3) = o3;
}

// ---------------------------------------------------------------------------
extern "C" void kernel_launch(void* const* d_in, const int* in_sizes, int n_in,
                              void* d_out, int out_size, void* d_ws, size_t ws_size,
                              hipStream_t stream) {
    const float* pos       = (const float*)d_in[0];
    const float* eq        = (const float*)d_in[1];
    const float* emb_table = (const float*)d_in[2];
    const float* w_phi1    = (const float*)d_in[3];
    const float* b_phi1    = (const float*)d_in[4];
    const float* w_phi2    = (const float*)d_in[5];
    const float* b_phi2    = (const float*)d_in[6];
    const float* w_rbf     = (const float*)d_in[7];
    const float* b_rbf     = (const float*)d_in[8];
    const int*   z         = (const int*)d_in[9];
    const int*   esrc      = (const int*)d_in[10];
    const int*   edst      = (const int*)d_in[11];

    float* out_emb = (float*)d_out;                               // [N, F]
    float* out_eq  = (float*)d_out + (size_t)N_NODES * F_DIM;     // [N, F, 3]

    // workspace layout (16B-aligned chunks)
    char* ws = (char*)d_ws;
    float4* rec        = (float4*)ws;  ws += (size_t)N_EDGES * 32;
    float*  phi_table  = (float*)ws;   ws += 100 * 3 * F_DIM * 4;
    float*  wT         = (float*)ws;   ws += N_RBF * F_DIM * 3 * 4;   // 30 KB
    int*    counts     = (int*)ws;     ws += N_NODES * 4;
    int*    partial    = (int*)ws;     ws += N_NODES * 4;
    int*    offsets    = (int*)ws;     ws += N_NODES * 4;
    int*    cursor     = (int*)ws;     ws += N_NODES * 4;
    int*    chunk_sums = (int*)ws;     ws += SCAN_B * 4;
    int*    chunk_pref = (int*)ws;     ws += SCAN_B * 4;

    hipMemsetAsync(counts, 0, N_NODES * sizeof(int), stream);
    phi_table_kernel<<<100, 3 * F_DIM, 0, stream>>>(emb_table, w_phi1, b_phi1,
                                                    w_phi2, b_phi2, phi_table);
    transpose_w_kernel<<<N_RBF, 3 * F_DIM, 0, stream>>>(w_rbf, wT);
    count_kernel<<<(N_EDGES + 255) / 256, 256, 0, stream>>>(edst, counts);
    scan_partial_kernel<<<N_CHUNK, SCAN_B, 0, stream>>>(counts, partial, chunk_sums);
    scan_sums_kernel<<<1, SCAN_B, 0, stream>>>(chunk_sums, chunk_pref);
    finalize_offsets_kernel<<<(N_NODES + 255) / 256, 256, 0, stream>>>(
        partial, chunk_pref, offsets, cursor);
    edge_pre_kernel<<<(N_EDGES + 255) / 256, 256, 0, stream>>>(
        pos, z, esrc, edst, cursor, rec);
    gather_kernel<<<(N_NODES + 1) / 2, 256, 0, stream>>>(
        eq, emb_table, phi_table, wT, b_rbf, z, rec,
        offsets, counts, out_emb, out_eq);
}

// Round 9
// 446.149 us; speedup vs baseline: 1.3245x; 1.1337x over previous
//
#include <hip/hip_runtime.h>
#include <math.h>

#define N_NODES 50000
#define N_EDGES 400000
#define F_DIM   128
#define N_RBF   20
#define SCAN_B  256
#define N_CHUNK ((N_NODES + SCAN_B - 1) / SCAN_B)   // 196

// ---------------------------------------------------------------------------
// phi_table[t] = silu(emb_table[t] @ w_phi1 + b_phi1) @ w_phi2 + b_phi2
// ---------------------------------------------------------------------------
__global__ void phi_table_kernel(const float* __restrict__ emb_table,
                                 const float* __restrict__ w_phi1,
                                 const float* __restrict__ b_phi1,
                                 const float* __restrict__ w_phi2,
                                 const float* __restrict__ b_phi2,
                                 float* __restrict__ phi_table) {
    __shared__ float emb_s[F_DIM];
    __shared__ float h_s[F_DIM];
    const int t = blockIdx.x;
    const int o = threadIdx.x;
    if (o < F_DIM) emb_s[o] = emb_table[t * F_DIM + o];
    __syncthreads();
    if (o < F_DIM) {
        float acc = b_phi1[o];
#pragma unroll 8
        for (int k = 0; k < F_DIM; ++k)
            acc = fmaf(emb_s[k], w_phi1[k * F_DIM + o], acc);
        h_s[o] = acc / (1.0f + expf(-acc));   // silu
    }
    __syncthreads();
    float a2 = b_phi2[o];
#pragma unroll 8
    for (int k = 0; k < F_DIM; ++k)
        a2 = fmaf(h_s[k], w_phi2[k * (3 * F_DIM) + o], a2);
    phi_table[t * (3 * F_DIM) + o] = a2;
}

__global__ void count_kernel(const int* __restrict__ edst, int* __restrict__ counts) {
    const int e = blockIdx.x * blockDim.x + threadIdx.x;
    if (e < N_EDGES) atomicAdd(&counts[edst[e]], 1);
}

__global__ void scan_partial_kernel(const int* __restrict__ counts,
                                    int* __restrict__ partial,
                                    int* __restrict__ chunk_sums) {
    __shared__ int s[SCAN_B];
    const int tid = threadIdx.x;
    const int gid = blockIdx.x * SCAN_B + tid;
    const int v = (gid < N_NODES) ? counts[gid] : 0;
    s[tid] = v;
    __syncthreads();
    for (int d = 1; d < SCAN_B; d <<= 1) {
        const int t = (tid >= d) ? s[tid - d] : 0;
        __syncthreads();
        s[tid] += t;
        __syncthreads();
    }
    if (gid < N_NODES) partial[gid] = s[tid] - v;
    if (tid == SCAN_B - 1) chunk_sums[blockIdx.x] = s[tid];
}

__global__ void scan_sums_kernel(int* __restrict__ chunk_sums,
                                 int* __restrict__ chunk_pref) {
    __shared__ int s[SCAN_B];
    const int tid = threadIdx.x;
    const int v = (tid < N_CHUNK) ? chunk_sums[tid] : 0;
    s[tid] = v;
    __syncthreads();
    for (int d = 1; d < SCAN_B; d <<= 1) {
        const int t = (tid >= d) ? s[tid - d] : 0;
        __syncthreads();
        s[tid] += t;
        __syncthreads();
    }
    if (tid < N_CHUNK) chunk_pref[tid] = s[tid] - v;
}

__global__ void finalize_offsets_kernel(const int* __restrict__ partial,
                                        const int* __restrict__ chunk_pref,
                                        int* __restrict__ offsets,
                                        int* __restrict__ cursor) {
    const int i = blockIdx.x * blockDim.x + threadIdx.x;
    if (i >= N_NODES) return;
    const int o = partial[i] + chunk_pref[i >> 8];
    offsets[i] = o;
    cursor[i]  = o;
}

// ---------------------------------------------------------------------------
// Edge-parallel precompute + CSR fill. Per edge, one 32B record at slot p:
//   rec[2p]   = (px, py, pz, d)
//   rec[2p+1] = (j, t, sin(a)/d, 2*cos(a))   [a = pi*d/5]
// ---------------------------------------------------------------------------
__global__ void edge_pre_kernel(const float* __restrict__ pos,
                                const int* __restrict__ z,
                                const int* __restrict__ esrc,
                                const int* __restrict__ edst,
                                int* __restrict__ cursor,
                                float4* __restrict__ rec) {
    const int e = blockIdx.x * blockDim.x + threadIdx.x;
    if (e >= N_EDGES) return;
    const int j = esrc[e];
    const int i = edst[e];
    const int p = atomicAdd(&cursor[i], 1);

    const float px = pos[3 * i + 0] - pos[3 * j + 0];
    const float py = pos[3 * i + 1] - pos[3 * j + 1];
    const float pz = pos[3 * i + 2] - pos[3 * j + 2];
    const float d = sqrtf(px * px + py * py + pz * pz);
    const float inv_d = 1.0f / d;

    float sa, ca;
    sincosf(0.6283185307179586f * d, &sa, &ca);   // pi*d/5

    rec[2 * p] = make_float4(px, py, pz, d);
    float4 b;
    b.x = __int_as_float(j);
    b.y = __int_as_float(z[j]);
    b.z = sa * inv_d;
    b.w = 2.0f * ca;
    rec[2 * p + 1] = b;
}

// ---------------------------------------------------------------------------
// Gather: 128-thread group per node (2/block). Thread f owns outputs
// f, 128+f, 256+f.
//
// R8 post-mortem: the cost was never the weight loads — it was their VGPR
// ADDRESS ARITHMETIC (64-bit adds per n), plus VGPR addressing on eq/phi/rec.
// R9 = R1's structure verbatim with scalar-base addressing:
//  * weight loads written as (w_rbf + n*384)[{0,128,256}+f]: uniform SGPR
//    base advanced by SALU per unrolled n, one shared voffset (f*4),
//    channel selects fold into 13-bit imm offsets {0,512,1024}. Zero VALU.
//  * j / t / start / cnt are wave-uniform (whole 128-group works one edge)
//    -> __builtin_amdgcn_readfirstlane moves them to SGPRs: eq/phi/rec
//    addressing becomes s[base]+voffset, loop control goes scalar.
// Per-edge VALU ~155 -> ~95 insts; VGPR pressure drops.
// ---------------------------------------------------------------------------
__global__ void __launch_bounds__(256, 2)
gather_kernel(const float* __restrict__ eq,
              const float* __restrict__ emb_table,
              const float* __restrict__ phi_table,
              const float* __restrict__ w_rbf,
              const float* __restrict__ b_rbf,
              const int* __restrict__ z,
              const float4* __restrict__ rec,
              const int* __restrict__ offsets,
              const int* __restrict__ counts,
              float* __restrict__ out_emb,
              float* __restrict__ out_eq) {
    const int tid = threadIdx.x;
    const int grp = tid >> 7;
    const int f   = tid & 127;
    const int i   = blockIdx.x * 2 + grp;
    if (i >= N_NODES) return;

    // wave-uniform CSR bounds -> SGPRs (scalar loop control, scalar rec base)
    const int start = __builtin_amdgcn_readfirstlane(offsets[i]);
    const int cnt   = __builtin_amdgcn_readfirstlane(counts[i]);

    const float br1 = b_rbf[f];
    const float br2 = b_rbf[F_DIM + f];
    const float br3 = b_rbf[2 * F_DIM + f];

    float accE = 0.f, ax = 0.f, ay = 0.f, az = 0.f;

    float4 A0, B0;
    float eq0, eq1, eq2, ph0, ph1, ph2;
    if (cnt > 0) {
        A0 = rec[2 * start];
        B0 = rec[2 * start + 1];
        const int j0 = __builtin_amdgcn_readfirstlane(__float_as_int(B0.x));
        const int t0 = __builtin_amdgcn_readfirstlane(__float_as_int(B0.y));
        const float* ej = eq + (size_t)j0 * (F_DIM * 3);       // uniform base
        eq0 = ej[f * 3 + 0]; eq1 = ej[f * 3 + 1]; eq2 = ej[f * 3 + 2];
        const float* pt = phi_table + t0 * (3 * F_DIM);        // uniform base
        ph0 = pt[f]; ph1 = pt[F_DIM + f]; ph2 = pt[2 * F_DIM + f];
    }

    for (int k = 0; k < cnt; ++k) {
        // prefetch next edge's record + gathers (overlaps the FMA block)
        float4 A1, B1;
        float neq0, neq1, neq2, nph0, nph1, nph2;
        if (k + 1 < cnt) {
            const int p1 = start + k + 1;                      // scalar
            A1 = rec[2 * p1];
            B1 = rec[2 * p1 + 1];
            const int j1 = __builtin_amdgcn_readfirstlane(__float_as_int(B1.x));
            const int t1 = __builtin_amdgcn_readfirstlane(__float_as_int(B1.y));
            const float* ej = eq + (size_t)j1 * (F_DIM * 3);   // uniform base
            neq0 = ej[f * 3 + 0]; neq1 = ej[f * 3 + 1]; neq2 = ej[f * 3 + 2];
            const float* pt = phi_table + t1 * (3 * F_DIM);    // uniform base
            nph0 = pt[f]; nph1 = pt[F_DIM + f]; nph2 = pt[2 * F_DIM + f];
        }

        // inner block: 60 saddr+imm loads (zero addr VALU) + 80 FMA
        float W1 = br1, W2 = br2, W3 = br3;
        float tm1 = 0.0f, tc = B0.z;
        const float twoc = B0.w;
#pragma unroll
        for (int n = 0; n < N_RBF; ++n) {
            const float* wrow = w_rbf + n * (3 * F_DIM);       // uniform base
            W1 = fmaf(tc, wrow[f], W1);
            W2 = fmaf(tc, wrow[F_DIM + f], W2);
            W3 = fmaf(tc, wrow[2 * F_DIM + f], W3);
            const float tn = fmaf(twoc, tc, -tm1);
            tm1 = tc; tc = tn;
        }

        accE += ph0 * W1;
        const float s2 = ph1 * W2;
        const float s3 = ph2 * W3 * A0.w;
        ax = fmaf(eq0, s2, fmaf(s3, A0.x, ax));
        ay = fmaf(eq1, s2, fmaf(s3, A0.y, ay));
        az = fmaf(eq2, s2, fmaf(s3, A0.z, az));

        if (k + 1 < cnt) {
            A0 = A1; B0 = B1;
            eq0 = neq0; eq1 = neq1; eq2 = neq2;
            ph0 = nph0; ph1 = nph1; ph2 = nph2;
        }
    }

    out_emb[(size_t)i * F_DIM + f] = emb_table[z[i] * F_DIM + f] + accE;

    const float* ei = eq     + ((size_t)i * F_DIM + f) * 3;
    float*       od = out_eq + ((size_t)i * F_DIM + f) * 3;
    od[0] = ei[0] + ax;
    od[1] = ei[1] + ay;
    od[2] = ei[2] + az;
}

// ---------------------------------------------------------------------------
extern "C" void kernel_launch(void* const* d_in, const int* in_sizes, int n_in,
                              void* d_out, int out_size, void* d_ws, size_t ws_size,
                              hipStream_t stream) {
    const float* pos       = (const float*)d_in[0];
    const float* eq        = (const float*)d_in[1];
    const float* emb_table = (const float*)d_in[2];
    const float* w_phi1    = (const float*)d_in[3];
    const float* b_phi1    = (const float*)d_in[4];
    const float* w_phi2    = (const float*)d_in[5];
    const float* b_phi2    = (const float*)d_in[6];
    const float* w_rbf     = (const float*)d_in[7];
    const float* b_rbf     = (const float*)d_in[8];
    const int*   z         = (const int*)d_in[9];
    const int*   esrc      = (const int*)d_in[10];
    const int*   edst      = (const int*)d_in[11];

    float* out_emb = (float*)d_out;                               // [N, F]
    float* out_eq  = (float*)d_out + (size_t)N_NODES * F_DIM;     // [N, F, 3]

    // workspace layout (16B-aligned chunks)
    char* ws = (char*)d_ws;
    float4* rec        = (float4*)ws;  ws += (size_t)N_EDGES * 32;
    float*  phi_table  = (float*)ws;   ws += 100 * 3 * F_DIM * 4;
    int*    counts     = (int*)ws;     ws += N_NODES * 4;
    int*    partial    = (int*)ws;     ws += N_NODES * 4;
    int*    offsets    = (int*)ws;     ws += N_NODES * 4;
    int*    cursor     = (int*)ws;     ws += N_NODES * 4;
    int*    chunk_sums = (int*)ws;     ws += SCAN_B * 4;
    int*    chunk_pref = (int*)ws;     ws += SCAN_B * 4;

    hipMemsetAsync(counts, 0, N_NODES * sizeof(int), stream);
    phi_table_kernel<<<100, 3 * F_DIM, 0, stream>>>(emb_table, w_phi1, b_phi1,
                                                    w_phi2, b_phi2, phi_table);
    count_kernel<<<(N_EDGES + 255) / 256, 256, 0, stream>>>(edst, counts);
    scan_partial_kernel<<<N_CHUNK, SCAN_B, 0, stream>>>(counts, partial, chunk_sums);
    scan_sums_kernel<<<1, SCAN_B, 0, stream>>>(chunk_sums, chunk_pref);
    finalize_offsets_kernel<<<(N_NODES + 255) / 256, 256, 0, stream>>>(
        partial, chunk_pref, offsets, cursor);
    edge_pre_kernel<<<(N_EDGES + 255) / 256, 256, 0, stream>>>(
        pos, z, esrc, edst, cursor, rec);
    gather_kernel<<<(N_NODES + 1) / 2, 256, 0, stream>>>(
        eq, emb_table, phi_table, w_rbf, b_rbf, z, rec,
        offsets, counts, out_emb, out_eq);
}